// Round 1
// baseline (359.159 us; speedup 1.0000x reference)
//
#include <hip/hip_runtime.h>
#include <hip/hip_bf16.h>

#define T_TOK 8192
#define DDIM  1024
#define NEXP  8

typedef __attribute__((ext_vector_type(8))) short bf16x8;
typedef __attribute__((ext_vector_type(4))) float f32x4;

__device__ inline unsigned short f2bf(float f) {
  union { float f; unsigned int u; } a; a.f = f;
  unsigned int u = a.u;
  unsigned int r = (u + 0x7fffu + ((u >> 16) & 1u)) >> 16;  // RNE
  return (unsigned short)r;
}

__device__ inline float bf2f(unsigned short u) {
  union { unsigned int u; float f; } a; a.u = ((unsigned int)u) << 16;
  return a.f;
}

__device__ inline void gload_lds16(const void* g, void* l) {
  __builtin_amdgcn_global_load_lds(
      (const __attribute__((address_space(1))) void*)g,
      (__attribute__((address_space(3))) void*)l, 16, 0, 0);
}

// ---------------- cast f32 -> bf16, float4 at a time ----------------
__global__ __launch_bounds__(256) void cast_bf16_kernel(
    const float* __restrict__ in, unsigned short* __restrict__ out, int n4) {
  int i = blockIdx.x * 256 + threadIdx.x;
  if (i >= n4) return;
  float4 v = reinterpret_cast<const float4*>(in)[i];
  ushort4 o;
  o.x = f2bf(v.x); o.y = f2bf(v.y); o.z = f2bf(v.z); o.w = f2bf(v.w);
  reinterpret_cast<ushort4*>(out)[i] = o;
}

// ---------------- gating: one wave per token ----------------
__global__ __launch_bounds__(256) void gate_kernel(
    const float* __restrict__ x, const float* __restrict__ gw,
    int* __restrict__ e_of, float* __restrict__ w_of, int* __restrict__ counts) {
  int t = blockIdx.x * 4 + (threadIdx.x >> 6);
  int lane = threadIdx.x & 63;
  const float* xr = x + (size_t)t * DDIM;
  float acc[NEXP];
#pragma unroll
  for (int e = 0; e < NEXP; ++e) acc[e] = 0.f;
  for (int c = 0; c < DDIM / 64; ++c) {
    float xv = xr[c * 64 + lane];
#pragma unroll
    for (int e = 0; e < NEXP; ++e)
      acc[e] += xv * gw[e * DDIM + c * 64 + lane];
  }
#pragma unroll
  for (int e = 0; e < NEXP; ++e) {
#pragma unroll
    for (int s = 32; s > 0; s >>= 1) acc[e] += __shfl_xor(acc[e], s);
  }
  if (lane == 0) {
    int e0 = 0; float v0 = acc[0];
#pragma unroll
    for (int e = 1; e < NEXP; ++e) if (acc[e] > v0) { v0 = acc[e]; e0 = e; }
    int e1 = (e0 == 0) ? 1 : 0; float v1 = acc[e1];
#pragma unroll
    for (int e = 0; e < NEXP; ++e)
      if (e != e0 && acc[e] > v1) { v1 = acc[e]; e1 = e; }
    float w1 = 1.f / (1.f + expf(v0 - v1));
    float w0 = 1.f - w1;
    e_of[2 * t] = e0; e_of[2 * t + 1] = e1;
    w_of[2 * t] = w0; w_of[2 * t + 1] = w1;
    atomicAdd(&counts[e0], 1);
    atomicAdd(&counts[e1], 1);
  }
}

// ---------------- prefix scan over E=8 ----------------
__global__ void scan_kernel(const int* __restrict__ counts,
                            int* __restrict__ offs, int* __restrict__ cursor) {
  if (threadIdx.x == 0) {
    int s = 0;
    for (int e = 0; e < NEXP; ++e) { offs[e] = s; cursor[e] = s; s += counts[e]; }
  }
}

// ---------------- build per-expert row lists ----------------
__global__ __launch_bounds__(256) void build_kernel(
    const int* __restrict__ e_of, int* __restrict__ cursor,
    int* __restrict__ row_src, int* __restrict__ tok_row) {
  int t = blockIdx.x * 256 + threadIdx.x;
  if (t >= T_TOK) return;
#pragma unroll
  for (int k = 0; k < 2; ++k) {
    int e = e_of[2 * t + k];
    int p = atomicAdd(&cursor[e], 1);
    row_src[p] = t;
    tok_row[2 * t + k] = p;
  }
}

// ---------------- grouped GEMM: Y[row] = xb[row_src[row]] @ Wb[e]^T ----------------
__global__ __launch_bounds__(256, 2) void gemm_kernel(
    const unsigned short* __restrict__ xb, const unsigned short* __restrict__ Wb,
    const int* __restrict__ row_src, const int* __restrict__ counts,
    const int* __restrict__ offs, unsigned short* __restrict__ Yb) {
  int e = blockIdx.z;
  int ce = counts[e];
  int m0 = blockIdx.y * 128;
  if (m0 >= ce) return;
  int base = offs[e];
  int n0 = blockIdx.x * 128;

  __shared__ unsigned short As[128 * 32];  // 8 KB, row-major [128][32]
  __shared__ unsigned short Bs[128 * 32];  // 8 KB

  int tid = threadIdx.x;
  int lane = tid & 63;
  int w = tid >> 6;           // 0..3
  int wr = w >> 1, wc = w & 1;

  // staging geometry: chunk q = w*2+c covers LDS rows [q*16, q*16+16)
  int q0 = w * 2, q1 = w * 2 + 1;
  int rl = lane >> 2;          // 0..15 row within chunk
  int col = (lane & 3) * 8;    // 0,8,16,24 (elements)
  int rA0 = q0 * 16 + rl, rA1 = q1 * 16 + rl;
  int i0 = m0 + rA0; if (i0 > ce - 1) i0 = ce - 1;
  int i1 = m0 + rA1; if (i1 > ce - 1) i1 = ce - 1;
  int tk0 = row_src[base + i0];
  int tk1 = row_src[base + i1];
  const unsigned short* gA0 = xb + (size_t)tk0 * DDIM + col;
  const unsigned short* gA1 = xb + (size_t)tk1 * DDIM + col;
  const unsigned short* We = Wb + (size_t)e * DDIM * DDIM;
  const unsigned short* gB0 = We + (size_t)(n0 + rA0) * DDIM + col;
  const unsigned short* gB1 = We + (size_t)(n0 + rA1) * DDIM + col;
  unsigned short* lA0 = As + q0 * 512;  // 1024 B chunks
  unsigned short* lA1 = As + q1 * 512;
  unsigned short* lB0 = Bs + q0 * 512;
  unsigned short* lB1 = Bs + q1 * 512;

  f32x4 acc[4][4];
#pragma unroll
  for (int m = 0; m < 4; ++m)
#pragma unroll
    for (int n = 0; n < 4; ++n) acc[m][n] = (f32x4){0.f, 0.f, 0.f, 0.f};

  int arow = wr * 64 + (lane & 15);
  int brow = wc * 64 + (lane & 15);
  int kb = (lane >> 4) * 8;

  for (int k0 = 0; k0 < DDIM; k0 += 32) {
    gload_lds16(gA0 + k0, lA0);
    gload_lds16(gA1 + k0, lA1);
    gload_lds16(gB0 + k0, lB0);
    gload_lds16(gB1 + k0, lB1);
    __syncthreads();

    bf16x8 af[4], bf[4];
#pragma unroll
    for (int m = 0; m < 4; ++m)
      af[m] = *reinterpret_cast<const bf16x8*>(&As[(arow + m * 16) * 32 + kb]);
#pragma unroll
    for (int n = 0; n < 4; ++n)
      bf[n] = *reinterpret_cast<const bf16x8*>(&Bs[(brow + n * 16) * 32 + kb]);
#pragma unroll
    for (int m = 0; m < 4; ++m)
#pragma unroll
      for (int n = 0; n < 4; ++n)
        acc[m][n] = __builtin_amdgcn_mfma_f32_16x16x32_bf16(af[m], bf[n], acc[m][n], 0, 0, 0);
    __syncthreads();
  }

  // epilogue: C/D layout col=lane&15, row=(lane>>4)*4+reg
  int crow = (lane >> 4) * 4;
  int ccol = lane & 15;
#pragma unroll
  for (int m = 0; m < 4; ++m) {
#pragma unroll
    for (int r = 0; r < 4; ++r) {
      int grow = m0 + wr * 64 + m * 16 + crow + r;
      if (grow < ce) {
        unsigned short* yr = Yb + (size_t)(base + grow) * DDIM + n0 + wc * 64 + ccol;
#pragma unroll
        for (int n = 0; n < 4; ++n)
          yr[n * 16] = f2bf(acc[m][n][r]);
      }
    }
  }
}

// ---------------- combine: out[t] = w0*Y[p0] + w1*Y[p1] ----------------
__global__ __launch_bounds__(256) void combine_kernel(
    const unsigned short* __restrict__ Yb, const int* __restrict__ tok_row,
    const float* __restrict__ w_of, float* __restrict__ out) {
  int t = blockIdx.x;
  int d = threadIdx.x * 4;
  int p0 = tok_row[2 * t], p1 = tok_row[2 * t + 1];
  float w0 = w_of[2 * t], w1 = w_of[2 * t + 1];
  ushort4 y0 = reinterpret_cast<const ushort4*>(Yb + (size_t)p0 * DDIM + d)[0];
  ushort4 y1 = reinterpret_cast<const ushort4*>(Yb + (size_t)p1 * DDIM + d)[0];
  float4 o;
  o.x = w0 * bf2f(y0.x) + w1 * bf2f(y1.x);
  o.y = w0 * bf2f(y0.y) + w1 * bf2f(y1.y);
  o.z = w0 * bf2f(y0.z) + w1 * bf2f(y1.z);
  o.w = w0 * bf2f(y0.w) + w1 * bf2f(y1.w);
  reinterpret_cast<float4*>(out + (size_t)t * DDIM + d)[0] = o;
}

extern "C" void kernel_launch(void* const* d_in, const int* in_sizes, int n_in,
                              void* d_out, int out_size, void* d_ws, size_t ws_size,
                              hipStream_t stream) {
  const float* x  = (const float*)d_in[0];
  const float* gw = (const float*)d_in[1];
  const float* ew = (const float*)d_in[2];
  float* out = (float*)d_out;
  char* ws = (char*)d_ws;

  unsigned short* xb = (unsigned short*)(ws);                    // 16 MB
  unsigned short* Wb = (unsigned short*)(ws + 16777216);         // 16 MB
  unsigned short* Yb = (unsigned short*)(ws + 33554432);         // 32 MB
  int*   e_of    = (int*)  (ws + 67108864);
  float* w_of    = (float*)(ws + 67174400);
  int*   row_src = (int*)  (ws + 67239936);
  int*   tok_row = (int*)  (ws + 67305472);
  int*   counts  = (int*)  (ws + 67371008);
  int*   offs    = (int*)  (ws + 67371040);
  int*   cursor  = (int*)  (ws + 67371072);

  hipMemsetAsync(counts, 0, 32, stream);

  int n4 = (T_TOK * DDIM) / 4;  // == (NEXP*DDIM*DDIM)/4 == 2097152
  cast_bf16_kernel<<<n4 / 256, 256, 0, stream>>>(x, xb, n4);
  cast_bf16_kernel<<<n4 / 256, 256, 0, stream>>>(ew, Wb, n4);

  gate_kernel<<<T_TOK / 4, 256, 0, stream>>>(x, gw, e_of, w_of, counts);
  scan_kernel<<<1, 64, 0, stream>>>(counts, offs, cursor);
  build_kernel<<<T_TOK / 256, 256, 0, stream>>>(e_of, cursor, row_src, tok_row);

  gemm_kernel<<<dim3(8, 64, 8), 256, 0, stream>>>(xb, Wb, row_src, counts, offs, Yb);

  combine_kernel<<<T_TOK, 256, 0, stream>>>(Yb, tok_row, w_of, out);
}

// Round 2
// 113.081 us; speedup vs baseline: 3.1761x; 3.1761x over previous
//
#include <hip/hip_runtime.h>
#include <hip/hip_bf16.h>

#define T_TOK 8192
#define DDIM  1024
#define NEXP  8

typedef __attribute__((ext_vector_type(8))) short bf16x8;
typedef __attribute__((ext_vector_type(4))) float f32x4;

__device__ inline unsigned short f2bf(float f) {
  union { float f; unsigned int u; } a; a.f = f;
  unsigned int u = a.u;
  unsigned int r = (u + 0x7fffu + ((u >> 16) & 1u)) >> 16;  // RNE
  return (unsigned short)r;
}

__device__ inline float bf2f(unsigned short u) {
  union { unsigned int u; float f; } a; a.u = ((unsigned int)u) << 16;
  return a.f;
}

__device__ inline void gload_lds16(const void* g, void* l) {
  __builtin_amdgcn_global_load_lds(
      (const __attribute__((address_space(1))) void*)g,
      (__attribute__((address_space(3))) void*)l, 16, 0, 0);
}

// ---------------- cast f32 -> bf16 (expert weights) ----------------
__global__ __launch_bounds__(256) void cast_bf16_kernel(
    const float* __restrict__ in, unsigned short* __restrict__ out, int n4) {
  int i = blockIdx.x * 256 + threadIdx.x;
  if (i >= n4) return;
  float4 v = reinterpret_cast<const float4*>(in)[i];
  ushort4 o;
  o.x = f2bf(v.x); o.y = f2bf(v.y); o.z = f2bf(v.z); o.w = f2bf(v.w);
  reinterpret_cast<ushort4*>(out)[i] = o;
}

// ---------------- gating (fused x->bf16 cast), NO global atomics ----------------
__global__ __launch_bounds__(256) void gate_kernel(
    const float* __restrict__ x, const float* __restrict__ gw,
    unsigned short* __restrict__ xb,
    int* __restrict__ e_of, float* __restrict__ w_of) {
  int t = blockIdx.x * 4 + (threadIdx.x >> 6);
  int lane = threadIdx.x & 63;
  const float4* xr = reinterpret_cast<const float4*>(x + (size_t)t * DDIM);
  ushort4* xbr = reinterpret_cast<ushort4*>(xb + (size_t)t * DDIM);
  float acc[NEXP];
#pragma unroll
  for (int e = 0; e < NEXP; ++e) acc[e] = 0.f;
#pragma unroll
  for (int c = 0; c < 4; ++c) {
    float4 xv = xr[c * 64 + lane];
    ushort4 o;
    o.x = f2bf(xv.x); o.y = f2bf(xv.y); o.z = f2bf(xv.z); o.w = f2bf(xv.w);
    xbr[c * 64 + lane] = o;
#pragma unroll
    for (int e = 0; e < NEXP; ++e) {
      float4 g = reinterpret_cast<const float4*>(gw + e * DDIM)[c * 64 + lane];
      acc[e] += xv.x * g.x + xv.y * g.y + xv.z * g.z + xv.w * g.w;
    }
  }
#pragma unroll
  for (int e = 0; e < NEXP; ++e) {
#pragma unroll
    for (int s = 32; s > 0; s >>= 1) acc[e] += __shfl_xor(acc[e], s);
  }
  if (lane == 0) {
    int e0 = 0; float v0 = acc[0];
#pragma unroll
    for (int e = 1; e < NEXP; ++e) if (acc[e] > v0) { v0 = acc[e]; e0 = e; }
    int e1 = (e0 == 0) ? 1 : 0; float v1 = acc[e1];
#pragma unroll
    for (int e = 0; e < NEXP; ++e)
      if (e != e0 && acc[e] > v1) { v1 = acc[e]; e1 = e; }
    float w1 = 1.f / (1.f + expf(v0 - v1));
    float w0 = 1.f - w1;
    e_of[2 * t] = e0; e_of[2 * t + 1] = e1;
    w_of[2 * t] = w0; w_of[2 * t + 1] = w1;
  }
}

// ---------------- counts: LDS histogram, 8 global atomics per block ----------------
__global__ __launch_bounds__(256) void count_kernel(
    const int* __restrict__ e_of, int* __restrict__ counts) {
  __shared__ int lc[NEXP];
  int tid = threadIdx.x;
  if (tid < NEXP) lc[tid] = 0;
  __syncthreads();
  int i = blockIdx.x * 512 + tid;
  atomicAdd(&lc[e_of[i]], 1);
  atomicAdd(&lc[e_of[i + 256]], 1);
  __syncthreads();
  if (tid < NEXP) atomicAdd(&counts[tid], lc[tid]);
}

// ---------------- prefix scan over E=8 ----------------
__global__ void scan_kernel(const int* __restrict__ counts,
                            int* __restrict__ offs, int* __restrict__ cursor) {
  if (threadIdx.x == 0) {
    int s = 0;
    for (int e = 0; e < NEXP; ++e) { offs[e] = s; cursor[e] = s; s += counts[e]; }
  }
}

// ---------------- build row lists: block-aggregated cursor atomics ----------------
__global__ __launch_bounds__(256) void build_kernel(
    const int* __restrict__ e_of, int* __restrict__ cursor,
    int* __restrict__ row_src, int* __restrict__ tok_row) {
  __shared__ int lc[NEXP];
  __shared__ int lbase[NEXP];
  int tid = threadIdx.x;
  if (tid < NEXP) lc[tid] = 0;
  __syncthreads();
  int i0 = blockIdx.x * 512 + tid;
  int i1 = i0 + 256;
  int ea = e_of[i0], eb = e_of[i1];
  int ra = atomicAdd(&lc[ea], 1);
  int rb = atomicAdd(&lc[eb], 1);
  __syncthreads();
  if (tid < NEXP) lbase[tid] = atomicAdd(&cursor[tid], lc[tid]);
  __syncthreads();
  int pa = lbase[ea] + ra;
  int pb = lbase[eb] + rb;
  row_src[pa] = i0 >> 1;
  tok_row[i0] = pa;
  row_src[pb] = i1 >> 1;
  tok_row[i1] = pb;
}

// ---------------- grouped GEMM: Y[row] = xb[row_src[row]] @ Wb[e]^T ----------------
__global__ __launch_bounds__(256, 2) void gemm_kernel(
    const unsigned short* __restrict__ xb, const unsigned short* __restrict__ Wb,
    const int* __restrict__ row_src, const int* __restrict__ counts,
    const int* __restrict__ offs, unsigned short* __restrict__ Yb) {
  int e = blockIdx.z;
  int ce = counts[e];
  int m0 = blockIdx.y * 128;
  if (m0 >= ce) return;
  int base = offs[e];
  int n0 = blockIdx.x * 128;

  __shared__ unsigned short As[128 * 32];  // 8 KB, row-major [128][32]
  __shared__ unsigned short Bs[128 * 32];  // 8 KB

  int tid = threadIdx.x;
  int lane = tid & 63;
  int w = tid >> 6;           // 0..3
  int wr = w >> 1, wc = w & 1;

  int q0 = w * 2, q1 = w * 2 + 1;
  int rl = lane >> 2;
  int col = (lane & 3) * 8;
  int rA0 = q0 * 16 + rl, rA1 = q1 * 16 + rl;
  int i0 = m0 + rA0; if (i0 > ce - 1) i0 = ce - 1;
  int i1 = m0 + rA1; if (i1 > ce - 1) i1 = ce - 1;
  int tk0 = row_src[base + i0];
  int tk1 = row_src[base + i1];
  const unsigned short* gA0 = xb + (size_t)tk0 * DDIM + col;
  const unsigned short* gA1 = xb + (size_t)tk1 * DDIM + col;
  const unsigned short* We = Wb + (size_t)e * DDIM * DDIM;
  const unsigned short* gB0 = We + (size_t)(n0 + rA0) * DDIM + col;
  const unsigned short* gB1 = We + (size_t)(n0 + rA1) * DDIM + col;
  unsigned short* lA0 = As + q0 * 512;
  unsigned short* lA1 = As + q1 * 512;
  unsigned short* lB0 = Bs + q0 * 512;
  unsigned short* lB1 = Bs + q1 * 512;

  f32x4 acc[4][4];
#pragma unroll
  for (int m = 0; m < 4; ++m)
#pragma unroll
    for (int n = 0; n < 4; ++n) acc[m][n] = (f32x4){0.f, 0.f, 0.f, 0.f};

  int arow = wr * 64 + (lane & 15);
  int brow = wc * 64 + (lane & 15);
  int kb = (lane >> 4) * 8;

  for (int k0 = 0; k0 < DDIM; k0 += 32) {
    gload_lds16(gA0 + k0, lA0);
    gload_lds16(gA1 + k0, lA1);
    gload_lds16(gB0 + k0, lB0);
    gload_lds16(gB1 + k0, lB1);
    __syncthreads();

    bf16x8 af[4], bf[4];
#pragma unroll
    for (int m = 0; m < 4; ++m)
      af[m] = *reinterpret_cast<const bf16x8*>(&As[(arow + m * 16) * 32 + kb]);
#pragma unroll
    for (int n = 0; n < 4; ++n)
      bf[n] = *reinterpret_cast<const bf16x8*>(&Bs[(brow + n * 16) * 32 + kb]);
#pragma unroll
    for (int m = 0; m < 4; ++m)
#pragma unroll
      for (int n = 0; n < 4; ++n)
        acc[m][n] = __builtin_amdgcn_mfma_f32_16x16x32_bf16(af[m], bf[n], acc[m][n], 0, 0, 0);
    __syncthreads();
  }

  int crow = (lane >> 4) * 4;
  int ccol = lane & 15;
#pragma unroll
  for (int m = 0; m < 4; ++m) {
#pragma unroll
    for (int r = 0; r < 4; ++r) {
      int grow = m0 + wr * 64 + m * 16 + crow + r;
      if (grow < ce) {
        unsigned short* yr = Yb + (size_t)(base + grow) * DDIM + n0 + wc * 64 + ccol;
#pragma unroll
        for (int n = 0; n < 4; ++n)
          yr[n * 16] = f2bf(acc[m][n][r]);
      }
    }
  }
}

// ---------------- combine: out[t] = w0*Y[p0] + w1*Y[p1] ----------------
__global__ __launch_bounds__(256) void combine_kernel(
    const unsigned short* __restrict__ Yb, const int* __restrict__ tok_row,
    const float* __restrict__ w_of, float* __restrict__ out) {
  int t = blockIdx.x;
  int d = threadIdx.x * 4;
  int p0 = tok_row[2 * t], p1 = tok_row[2 * t + 1];
  float w0 = w_of[2 * t], w1 = w_of[2 * t + 1];
  ushort4 y0 = reinterpret_cast<const ushort4*>(Yb + (size_t)p0 * DDIM + d)[0];
  ushort4 y1 = reinterpret_cast<const ushort4*>(Yb + (size_t)p1 * DDIM + d)[0];
  float4 o;
  o.x = w0 * bf2f(y0.x) + w1 * bf2f(y1.x);
  o.y = w0 * bf2f(y0.y) + w1 * bf2f(y1.y);
  o.z = w0 * bf2f(y0.z) + w1 * bf2f(y1.z);
  o.w = w0 * bf2f(y0.w) + w1 * bf2f(y1.w);
  reinterpret_cast<float4*>(out + (size_t)t * DDIM + d)[0] = o;
}

extern "C" void kernel_launch(void* const* d_in, const int* in_sizes, int n_in,
                              void* d_out, int out_size, void* d_ws, size_t ws_size,
                              hipStream_t stream) {
  const float* x  = (const float*)d_in[0];
  const float* gw = (const float*)d_in[1];
  const float* ew = (const float*)d_in[2];
  float* out = (float*)d_out;
  char* ws = (char*)d_ws;

  unsigned short* xb = (unsigned short*)(ws);                    // 16 MB
  unsigned short* Wb = (unsigned short*)(ws + 16777216);         // 16 MB
  unsigned short* Yb = (unsigned short*)(ws + 33554432);         // 32 MB
  int*   e_of    = (int*)  (ws + 67108864);
  float* w_of    = (float*)(ws + 67174400);
  int*   row_src = (int*)  (ws + 67239936);
  int*   tok_row = (int*)  (ws + 67305472);
  int*   counts  = (int*)  (ws + 67371008);
  int*   offs    = (int*)  (ws + 67371040);
  int*   cursor  = (int*)  (ws + 67371072);

  hipMemsetAsync(counts, 0, 32, stream);

  int n4w = (NEXP * DDIM * DDIM) / 4;
  cast_bf16_kernel<<<n4w / 256, 256, 0, stream>>>(ew, Wb, n4w);

  gate_kernel<<<T_TOK / 4, 256, 0, stream>>>(x, gw, xb, e_of, w_of);
  count_kernel<<<32, 256, 0, stream>>>(e_of, counts);
  scan_kernel<<<1, 64, 0, stream>>>(counts, offs, cursor);
  build_kernel<<<32, 256, 0, stream>>>(e_of, cursor, row_src, tok_row);

  gemm_kernel<<<dim3(8, 64, 8), 256, 0, stream>>>(xb, Wb, row_src, counts, offs, Yb);

  combine_kernel<<<T_TOK, 256, 0, stream>>>(Yb, tok_row, w_of, out);
}